// Round 17
// baseline (435.952 us; speedup 1.0000x reference)
//
#include <hip/hip_runtime.h>
#include <hip/hip_bf16.h>

#define NN 100000
#define EE 1600000
#define DD 128
#define GG 128
#define CC 10
#define NPB 256      // nodes per bucket (power of 2)
#define NB 391       // ceil(NN/NPB)
#define SCAP 5120    // LDS slot capacity per bucket (mean 4092, sigma ~64)
#define VPT 16       // edges per thread in k_bcount/k_part
#define CPAD 32      // padded counter stride (ints) = 128B per counter
#define PPN 64       // nodes per pool block

typedef __attribute__((ext_vector_type(8))) short bf16x8;
typedef __attribute__((ext_vector_type(4))) float f32x4;
typedef __attribute__((ext_vector_type(2))) float f32x2;
typedef unsigned int u32;

__device__ inline float blo(u32 u) { return __uint_as_float(u << 16); }
__device__ inline float bhi(u32 u) { return __uint_as_float(u & 0xffff0000u); }
// pack two floats to bf16x2 (RNE)
__device__ inline u32 bpack(float x, float y) {
    u32 bx = __float_as_uint(x);
    u32 by = __float_as_uint(y);
    bx = (bx + 0x7fffu + ((bx >> 16) & 1u)) >> 16;
    by = (by + 0x7fffu + ((by >> 16) & 1u)) & 0xffff0000u;
    return bx | by;
}

// ---------- bucket histogram: block-aggregated, padded counters ----------
__global__ __launch_bounds__(256) void k_bcount(const int* __restrict__ col,
                                                int* __restrict__ bhist) {
    __shared__ int lh[NB];
    int tid = threadIdx.x;
    for (int b = tid; b < NB; b += 256) lh[b] = 0;
    __syncthreads();
    int base = blockIdx.x * (256 * VPT);
#pragma unroll
    for (int j = 0; j < VPT; j++) {
        int e = base + j * 256 + tid;
        if (e < EE) atomicAdd(&lh[col[e] >> 8], 1);
    }
    __syncthreads();
    for (int b = tid; b < NB; b += 256) {
        int h = lh[b];
        if (h) atomicAdd(&bhist[b * CPAD], h);
    }
}

// ---------- bucket exclusive scan (single block, 512 threads) ----------
__global__ __launch_bounds__(512) void k_bscan(const int* __restrict__ bhist,
                                               int* __restrict__ boffs,
                                               int* __restrict__ bcur) {
    __shared__ int s[512];
    int tid = threadIdx.x;
    int c = (tid < NB) ? bhist[tid * CPAD] : 0;
    s[tid] = c;
    __syncthreads();
    for (int off = 1; off < 512; off <<= 1) {
        int v = (tid >= off) ? s[tid - off] : 0;
        __syncthreads();
        s[tid] += v;
        __syncthreads();
    }
    int excl = s[tid] - c;
    if (tid < NB) {
        boffs[tid] = excl;
        bcur[tid * CPAD] = excl;
    }
    if (tid == NB - 1) boffs[NB] = excl + c;  // == EE
}

// ---------- partition edges into bucket regions (packed r<<8 | c&255) ----------
__global__ __launch_bounds__(256) void k_part(const int* __restrict__ row, const int* __restrict__ col,
                                              int* __restrict__ bcur, u32* __restrict__ pairs) {
    __shared__ int lhist[NB];
    __shared__ int gbase[NB];
    __shared__ int lcur[NB];
    int tid = threadIdx.x;
    for (int b = tid; b < NB; b += 256) lhist[b] = 0;
    __syncthreads();
    int base = blockIdx.x * (256 * VPT);
    u32 v[VPT];
    int bb[VPT];
#pragma unroll
    for (int j = 0; j < VPT; j++) {
        int e = base + j * 256 + tid;
        if (e < EE) {
            int r = row[e], c = col[e];
            v[j] = ((u32)r << 8) | (u32)(c & 255);
            bb[j] = c >> 8;
            atomicAdd(&lhist[bb[j]], 1);
        } else {
            bb[j] = -1;
        }
    }
    __syncthreads();
    for (int b = tid; b < NB; b += 256) {
        int h = lhist[b];
        gbase[b] = h ? atomicAdd(&bcur[b * CPAD], h) : 0;
        lcur[b] = 0;
    }
    __syncthreads();
#pragma unroll
    for (int j = 0; j < VPT; j++) {
        if (bb[j] >= 0) {
            int slot = gbase[bb[j]] + atomicAdd(&lcur[bb[j]], 1);
            pairs[slot] = v[j];
        }
    }
}

// ---------- per-bucket: node counts -> offs+dis, LDS counting sort -> src ----------
__global__ __launch_bounds__(256) void k_sort(const u32* __restrict__ pairs,
                                              const int* __restrict__ boffs,
                                              int* __restrict__ offs,
                                              float* __restrict__ dis,
                                              int* __restrict__ src) {
    int b = blockIdx.x;
    int tid = threadIdx.x;
    int nstart = b << 8;
    int nvalid = NN - nstart;           // valid nodes in this bucket
    if (nvalid > NPB) nvalid = NPB;
    int base = boffs[b];
    int eend = boffs[b + 1];
    int cnt = eend - base;
    __shared__ int lcnt[NPB];
    __shared__ int lscan[NPB];
    __shared__ int lcur[NPB];
    __shared__ int lsrc[SCAP];
    lcnt[tid] = 0;
    __syncthreads();
    for (int e = base + tid; e < eend; e += 256)
        atomicAdd(&lcnt[pairs[e] & 255u], 1);
    __syncthreads();
    int c = lcnt[tid];
    lscan[tid] = c;
    __syncthreads();
    for (int off = 1; off < 256; off <<= 1) {
        int v = (tid >= off) ? lscan[tid - off] : 0;
        __syncthreads();
        lscan[tid] += v;
        __syncthreads();
    }
    int excl = lscan[tid] - c;
    if (tid < nvalid) {
        offs[nstart + tid] = base + excl;
        dis[nstart + tid] = rsqrtf((float)(c + 1));  // degree includes self-loop
    }
    if (b == NB - 1 && tid == 255) offs[NN] = EE;
    lcur[tid] = excl;
    __syncthreads();
    if (cnt <= SCAP) {
        for (int e = base + tid; e < eend; e += 256) {
            u32 v = pairs[e];
            int slot = atomicAdd(&lcur[v & 255u], 1);
            lsrc[slot] = (int)(v >> 8);
        }
        __syncthreads();
        for (int i = tid; i < cnt; i += 256)
            src[base + i] = lsrc[i];
    } else {
        // fallback (not expected on this input): place directly to global
        for (int e = base + tid; e < eend; e += 256) {
            u32 v = pairs[e];
            int slot = base + atomicAdd(&lcur[v & 255u], 1);
            src[slot] = (int)(v >> 8);
        }
    }
}

// ---------- params prep: W^T -> bf16 with BN scale folded into columns ----------
__global__ void k_prep(const float* __restrict__ Wc, const float* __restrict__ bc,
                       const float* __restrict__ gamma, const float* __restrict__ beta,
                       const float* __restrict__ mean, const float* __restrict__ var,
                       __hip_bfloat16* __restrict__ WT,
                       float* __restrict__ tc) {
    int i = blockIdx.x * 256 + threadIdx.x;
    if (i < 3 * 128) {
        int l = i >> 7, d = i & 127;
        float t;
        if (l < 2) {
            float s = gamma[l * 128 + d] * rsqrtf(var[l * 128 + d] + 1e-5f);
            t = (bc[l * 128 + d] - mean[l * 128 + d]) * s + beta[l * 128 + d];
        } else {
            t = bc[2 * 128 + d];
        }
        tc[i] = t;
    }
    if (i < 3 * 16384) {
        int l = i >> 14, r = (i >> 7) & 127, k = i & 127;
        float s = 1.f;
        if (l < 2) s = gamma[l * 128 + r] * rsqrtf(var[l * 128 + r] + 1e-5f);
        // WT[l][r][k] = W[l][k][r] * sc[l][r]  (BN scale folded into output column)
        WT[i] = __float2bfloat16(Wc[l * 16384 + k * 128 + r] * s);
    }
}

// ---------- pre: hs0 = bf16(dis[n] * x[n,:]) ----------
__global__ __launch_bounds__(256) void k_pre(const float* __restrict__ x,
                                             const float* __restrict__ dis,
                                             u32* __restrict__ hs) {
    int i = blockIdx.x * 256 + threadIdx.x;   // u32 slot: node = i>>6
    if (i < NN * 64) {
        float dn = dis[i >> 6];
        float2 v = ((const float2*)x)[i];
        hs[i] = bpack(v.x * dn, v.y * dn);
    }
}

// ---------- fused aggregate + transform v3: wave-autonomous, NO barrier ----------
// Each wave owns 8 consecutive nodes: gathers into its PRIVATE LDS slice, then
// MFMA-transforms its own 8x128 tile (A rows 8-15 duplicate rows 0-7 via lr&7;
// garbage C rows >=8 never written — row-local in A@B so no contamination).
// No __syncthreads: all LDS deps are wave-local (lockstep wave64 + lgkmcnt).
template <int PRESCALE>
__global__ __launch_bounds__(256) void k_aggW(const u32* __restrict__ hin,
                                              const int* __restrict__ offs,
                                              const int* __restrict__ src,
                                              const float* __restrict__ dis,
                                              const __hip_bfloat16* __restrict__ WT,
                                              const float* __restrict__ tc,
                                              u32* __restrict__ hout) {
    __shared__ u32   Atile[4][8][68];     // per-wave slice, bf16x2, padded
    __shared__ float Otile[4][8][132];    // per-wave slice, padded
    int tid = threadIdx.x;
    int w = tid >> 6, lane = tid & 63;
    int base = blockIdx.x * 32 + w * 8;   // NN = 3125*32 exactly
    float dns[8];
#pragma unroll
    for (int i = 0; i < 8; i++) {
        int node = base + i;
        int e0 = __builtin_amdgcn_readfirstlane(offs[node]);
        int e1 = __builtin_amdgcn_readfirstlane(offs[node + 1]);
        u32 self = hin[((u32)node << 6) + lane];
        f32x2 acc = {blo(self), bhi(self)};
        int e = e0;
        for (; e + 16 <= e1; e += 16) {
            u32 u[16];
#pragma unroll
            for (int j = 0; j < 16; j++) {
                u32 s = (u32)src[e + j];
                u[j] = hin[(s << 6) + lane];
            }
#pragma unroll
            for (int j = 0; j < 16; j++) {
                f32x2 v = {blo(u[j]), bhi(u[j])};
                acc += v;
            }
        }
        for (; e + 8 <= e1; e += 8) {
            u32 u[8];
#pragma unroll
            for (int j = 0; j < 8; j++) {
                u32 s = (u32)src[e + j];
                u[j] = hin[(s << 6) + lane];
            }
#pragma unroll
            for (int j = 0; j < 8; j++) {
                f32x2 v = {blo(u[j]), bhi(u[j])};
                acc += v;
            }
        }
        for (; e < e1; e++) {
            u32 u = hin[((u32)src[e] << 6) + lane];
            f32x2 v = {blo(u), bhi(u)};
            acc += v;
        }
        float dn = dis[node];
        dns[i] = dn;
        Atile[w][i][lane] = bpack(acc.x * dn, acc.y * dn);
    }
    // wave-local MFMA over own 8-row tile (A rows 8-15 = duplicates via lr&7)
    int lg = lane >> 4, lr = lane & 15;
#pragma unroll
    for (int ct = 0; ct < 8; ct++) {
        f32x4 c4 = {0.f, 0.f, 0.f, 0.f};
#pragma unroll
        for (int kk = 0; kk < 4; kk++) {
            bf16x8 a = *(const bf16x8*)&Atile[w][lr & 7][kk * 16 + lg * 4];
            bf16x8 b = *(const bf16x8*)(WT + (size_t)(ct * 16 + lr) * 128 + kk * 32 + lg * 8);
            c4 = __builtin_amdgcn_mfma_f32_16x16x32_bf16(a, b, c4, 0, 0, 0);
        }
        // C/D: col = lane&15 (-> global col ct*16+lr), row = lg*4+r; keep rows<8
        if (lg < 2) {
#pragma unroll
            for (int r = 0; r < 4; r++)
                Otile[w][lg * 4 + r][ct * 16 + lr] = c4[r];
        }
    }
    // epilogue: coalesced row writes (wave-local LDS reads)
    int d0 = lane * 2;
    float t0 = tc[d0], t1 = tc[d0 + 1];
#pragma unroll
    for (int i = 0; i < 8; i++) {
        float r0 = Otile[w][i][d0]     + t0;
        float r1 = Otile[w][i][d0 + 1] + t1;
        r0 = r0 > 0.f ? r0 : 0.03f * r0;
        r1 = r1 > 0.f ? r1 : 0.03f * r1;
        if (PRESCALE) { r0 *= dns[i]; r1 *= dns[i]; }
        hout[((u32)(base + i) << 6) + lane] = bpack(r0, r1);
    }
}

// ---------- global mean pool: parallel partial sums (batch sorted) ----------
__global__ __launch_bounds__(64) void k_pool(const u32* __restrict__ h,
                                             const int* __restrict__ batch,
                                             float* __restrict__ pooled,
                                             float* __restrict__ counts) {
    int lane = threadIdx.x;  // covers 2 feature cols
    int n0 = blockIdx.x * PPN;
    if (n0 >= NN) return;
    int n1 = n0 + PPN;
    if (n1 > NN) n1 = NN;
    float a0 = 0.f, a1 = 0.f, cnt = 0.f;
    int g = batch[n0];
    for (int n = n0; n < n1; n++) {
        int bg = batch[n];
        if (bg != g) {
            atomicAdd(&pooled[g * 128 + lane * 2], a0);
            atomicAdd(&pooled[g * 128 + lane * 2 + 1], a1);
            if (lane == 0) atomicAdd(&counts[g], cnt);
            a0 = 0.f; a1 = 0.f; cnt = 0.f; g = bg;
        }
        u32 u = h[(u32)n * 64u + lane];
        a0 += blo(u); a1 += bhi(u);
        cnt += 1.f;
    }
    atomicAdd(&pooled[g * 128 + lane * 2], a0);
    atomicAdd(&pooled[g * 128 + lane * 2 + 1], a1);
    if (lane == 0) atomicAdd(&counts[g], cnt);
}

// ---------- head ----------
__global__ void k_head(const float* __restrict__ pooled, const float* __restrict__ counts,
                       const float* __restrict__ w, const float* __restrict__ b,
                       float* __restrict__ out) {
    int i = blockIdx.x * blockDim.x + threadIdx.x;
    if (i >= GG * CC) return;
    int g = i / CC, c = i % CC;
    float cnt = counts[g];
    cnt = cnt > 1.f ? cnt : 1.f;
    float inv = 1.f / cnt;
    const float* p = &pooled[g * 128];
    const float* ww = &w[c * 128];
    float acc = 0.f;
    for (int d = 0; d < 128; d++) acc += p[d] * ww[d];
    out[i] = acc * inv + b[c];
}

extern "C" void kernel_launch(void* const* d_in, const int* in_sizes, int n_in,
                              void* d_out, int out_size, void* d_ws, size_t ws_size,
                              hipStream_t stream) {
    const float* x     = (const float*)d_in[0];
    const int*   ei    = (const int*)d_in[1];
    const int*   row   = ei;
    const int*   col   = ei + EE;
    const int*   batch = (const int*)d_in[2];
    const float* Wc    = (const float*)d_in[3];
    const float* bc    = (const float*)d_in[4];
    const float* gamma = (const float*)d_in[5];
    const float* beta  = (const float*)d_in[6];
    const float* mean  = (const float*)d_in[7];
    const float* var   = (const float*)d_in[8];
    const float* lw    = (const float*)d_in[9];
    const float* lb    = (const float*)d_in[10];
    float* out = (float*)d_out;

    char* p = (char*)d_ws;
    auto alloc = [&](size_t bytes) -> char* {
        char* r = p;
        p += (bytes + 255) & ~(size_t)255;
        return r;
    };
    float* dis    = (float*)alloc((size_t)NN * 4);
    int*   offs   = (int*)alloc((size_t)(NN + 1) * 4);
    int*   bhist  = (int*)alloc((size_t)NB * CPAD * 4);
    int*   boffs  = (int*)alloc((size_t)(NB + 1) * 4);
    int*   bcur   = (int*)alloc((size_t)NB * CPAD * 4);
    int*   src    = (int*)alloc((size_t)EE * 4);
    __hip_bfloat16* WT = (__hip_bfloat16*)alloc((size_t)3 * 16384 * 2);
    float* tc     = (float*)alloc((size_t)3 * 128 * 4);
    float* pooled = (float*)alloc((size_t)GG * 128 * 4);
    float* counts = (float*)alloc((size_t)GG * 4);
    __hip_bfloat16* h0b = (__hip_bfloat16*)alloc((size_t)NN * 128 * 2);
    __hip_bfloat16* h1b = (__hip_bfloat16*)alloc((size_t)NN * 128 * 2);
    u32* pairs = (u32*)h0b;  // alias: pairs dead before k_pre writes h0b

    hipMemsetAsync(bhist, 0, (size_t)NB * CPAD * 4, stream);
    hipMemsetAsync(pooled, 0, (size_t)GG * 128 * 4, stream);
    hipMemsetAsync(counts, 0, (size_t)GG * 4, stream);

    const int eb_grid = (EE + 256 * VPT - 1) / (256 * VPT);
    k_bcount<<<eb_grid, 256, 0, stream>>>(col, bhist);
    k_bscan<<<1, 512, 0, stream>>>(bhist, boffs, bcur);
    k_part<<<eb_grid, 256, 0, stream>>>(row, col, bcur, pairs);
    k_sort<<<NB, 256, 0, stream>>>(pairs, boffs, offs, dis, src);
    k_prep<<<192, 256, 0, stream>>>(Wc, bc, gamma, beta, mean, var, WT, tc);
    k_pre<<<(NN * 64 + 255) / 256, 256, 0, stream>>>(x, dis, (u32*)h0b);  // after k_sort (pairs alias)

    const int fused_grid = NN / 32;  // 3125, exact

    k_aggW<1><<<fused_grid, 256, 0, stream>>>((const u32*)h0b, offs, src, dis, WT,           tc,       (u32*)h1b);
    k_aggW<1><<<fused_grid, 256, 0, stream>>>((const u32*)h1b, offs, src, dis, WT + 16384,   tc + 128, (u32*)h0b);
    k_aggW<0><<<fused_grid, 256, 0, stream>>>((const u32*)h0b, offs, src, dis, WT + 2*16384, tc + 256, (u32*)h1b);

    k_pool<<<(NN + PPN - 1) / PPN, 64, 0, stream>>>((const u32*)h1b, batch, pooled, counts);
    k_head<<<(GG * CC + 255) / 256, 256, 0, stream>>>(pooled, counts, lw, lb, out);
}

// Round 18
// 426.664 us; speedup vs baseline: 1.0218x; 1.0218x over previous
//
#include <hip/hip_runtime.h>
#include <hip/hip_bf16.h>

#define NN 100000
#define EE 1600000
#define DD 128
#define GG 128
#define CC 10
#define NPB 256      // nodes per bucket (power of 2)
#define NB 391       // ceil(NN/NPB)
#define SCAP 5120    // LDS slot capacity per bucket (mean 4092, sigma ~64)
#define VPT 4        // edges per thread in k_bcount/k_part (1563 blocks: TLP for atomics)
#define CPAD 32      // padded counter stride (ints) = 128B per counter
#define PPN 64       // nodes per pool block

typedef __attribute__((ext_vector_type(8))) short bf16x8;
typedef __attribute__((ext_vector_type(4))) float f32x4;
typedef __attribute__((ext_vector_type(2))) float f32x2;
typedef unsigned int u32;

__device__ inline float blo(u32 u) { return __uint_as_float(u << 16); }
__device__ inline float bhi(u32 u) { return __uint_as_float(u & 0xffff0000u); }
// pack two floats to bf16x2 (RNE)
__device__ inline u32 bpack(float x, float y) {
    u32 bx = __float_as_uint(x);
    u32 by = __float_as_uint(y);
    bx = (bx + 0x7fffu + ((bx >> 16) & 1u)) >> 16;
    by = (by + 0x7fffu + ((by >> 16) & 1u)) & 0xffff0000u;
    return bx | by;
}

// ---------- bucket histogram: block-aggregated, padded counters ----------
__global__ __launch_bounds__(256) void k_bcount(const int* __restrict__ col,
                                                int* __restrict__ bhist) {
    __shared__ int lh[NB];
    int tid = threadIdx.x;
    for (int b = tid; b < NB; b += 256) lh[b] = 0;
    __syncthreads();
    int base = blockIdx.x * (256 * VPT);
#pragma unroll
    for (int j = 0; j < VPT; j++) {
        int e = base + j * 256 + tid;
        if (e < EE) atomicAdd(&lh[col[e] >> 8], 1);
    }
    __syncthreads();
    for (int b = tid; b < NB; b += 256) {
        int h = lh[b];
        if (h) atomicAdd(&bhist[b * CPAD], h);
    }
}

// ---------- bucket exclusive scan (single block, 512 threads) ----------
__global__ __launch_bounds__(512) void k_bscan(const int* __restrict__ bhist,
                                               int* __restrict__ boffs,
                                               int* __restrict__ bcur) {
    __shared__ int s[512];
    int tid = threadIdx.x;
    int c = (tid < NB) ? bhist[tid * CPAD] : 0;
    s[tid] = c;
    __syncthreads();
    for (int off = 1; off < 512; off <<= 1) {
        int v = (tid >= off) ? s[tid - off] : 0;
        __syncthreads();
        s[tid] += v;
        __syncthreads();
    }
    int excl = s[tid] - c;
    if (tid < NB) {
        boffs[tid] = excl;
        bcur[tid * CPAD] = excl;
    }
    if (tid == NB - 1) boffs[NB] = excl + c;  // == EE
}

// ---------- partition edges into bucket regions (packed r<<8 | c&255) ----------
__global__ __launch_bounds__(256) void k_part(const int* __restrict__ row, const int* __restrict__ col,
                                              int* __restrict__ bcur, u32* __restrict__ pairs) {
    __shared__ int lhist[NB];
    __shared__ int gbase[NB];
    __shared__ int lcur[NB];
    int tid = threadIdx.x;
    for (int b = tid; b < NB; b += 256) lhist[b] = 0;
    __syncthreads();
    int base = blockIdx.x * (256 * VPT);
    u32 v[VPT];
    int bb[VPT];
#pragma unroll
    for (int j = 0; j < VPT; j++) {
        int e = base + j * 256 + tid;
        if (e < EE) {
            int r = row[e], c = col[e];
            v[j] = ((u32)r << 8) | (u32)(c & 255);
            bb[j] = c >> 8;
            atomicAdd(&lhist[bb[j]], 1);
        } else {
            bb[j] = -1;
        }
    }
    __syncthreads();
    for (int b = tid; b < NB; b += 256) {
        int h = lhist[b];
        gbase[b] = h ? atomicAdd(&bcur[b * CPAD], h) : 0;
        lcur[b] = 0;
    }
    __syncthreads();
#pragma unroll
    for (int j = 0; j < VPT; j++) {
        if (bb[j] >= 0) {
            int slot = gbase[bb[j]] + atomicAdd(&lcur[bb[j]], 1);
            pairs[slot] = v[j];
        }
    }
}

// ---------- per-bucket: offs+dis, LDS counting sort -> src, in-bucket degree perm ----------
__global__ __launch_bounds__(256) void k_sort(const u32* __restrict__ pairs,
                                              const int* __restrict__ boffs,
                                              int* __restrict__ offs,
                                              float* __restrict__ dis,
                                              int* __restrict__ src,
                                              int* __restrict__ perm) {
    int b = blockIdx.x;
    int tid = threadIdx.x;
    int nstart = b << 8;
    int nvalid = NN - nstart;           // valid nodes in this bucket
    if (nvalid > NPB) nvalid = NPB;
    int base = boffs[b];
    int eend = boffs[b + 1];
    int cnt = eend - base;
    __shared__ int lcnt[NPB];
    __shared__ int lscan[NPB];
    __shared__ int lcur[NPB];
    __shared__ int dh2[NPB];
    __shared__ int lsrc[SCAP];
    lcnt[tid] = 0;
    __syncthreads();
    for (int e = base + tid; e < eend; e += 256)
        atomicAdd(&lcnt[pairs[e] & 255u], 1);
    __syncthreads();
    int c = lcnt[tid];
    lscan[tid] = c;
    __syncthreads();
    for (int off = 1; off < 256; off <<= 1) {
        int v = (tid >= off) ? lscan[tid - off] : 0;
        __syncthreads();
        lscan[tid] += v;
        __syncthreads();
    }
    int excl = lscan[tid] - c;
    if (tid < nvalid) {
        offs[nstart + tid] = base + excl;
        dis[nstart + tid] = rsqrtf((float)(c + 1));  // degree includes self-loop
    }
    if (b == NB - 1 && tid == 255) offs[NN] = EE;
    lcur[tid] = excl;
    __syncthreads();
    if (cnt <= SCAP) {
        for (int e = base + tid; e < eend; e += 256) {
            u32 v = pairs[e];
            int slot = atomicAdd(&lcur[v & 255u], 1);
            lsrc[slot] = (int)(v >> 8);
        }
        __syncthreads();
        for (int i = tid; i < cnt; i += 256)
            src[base + i] = lsrc[i];
    } else {
        // fallback (not expected on this input): place directly to global
        for (int e = base + tid; e < eend; e += 256) {
            u32 v = pairs[e];
            int slot = base + atomicAdd(&lcur[v & 255u], 1);
            src[slot] = (int)(v >> 8);
        }
    }
    // ---- in-bucket degree sort -> perm (locality + straggler balance) ----
    int dc = c > 255 ? 255 : c;
    dh2[tid] = 0;
    __syncthreads();
    if (tid < nvalid) atomicAdd(&dh2[dc], 1);
    __syncthreads();
    int hc = dh2[tid];
    lscan[tid] = hc;
    __syncthreads();
    for (int off = 1; off < 256; off <<= 1) {
        int v = (tid >= off) ? lscan[tid - off] : 0;
        __syncthreads();
        lscan[tid] += v;
        __syncthreads();
    }
    dh2[tid] = lscan[tid] - hc;   // reuse dh2 as per-degree cursor (init = excl prefix)
    __syncthreads();
    if (tid < nvalid) {
        int slot = atomicAdd(&dh2[dc], 1);
        perm[nstart + slot] = nstart + tid;
    }
}

// ---------- params prep: W^T -> bf16 with BN scale folded into columns ----------
__global__ void k_prep(const float* __restrict__ Wc, const float* __restrict__ bc,
                       const float* __restrict__ gamma, const float* __restrict__ beta,
                       const float* __restrict__ mean, const float* __restrict__ var,
                       __hip_bfloat16* __restrict__ WT,
                       float* __restrict__ tc) {
    int i = blockIdx.x * 256 + threadIdx.x;
    if (i < 3 * 128) {
        int l = i >> 7, d = i & 127;
        float t;
        if (l < 2) {
            float s = gamma[l * 128 + d] * rsqrtf(var[l * 128 + d] + 1e-5f);
            t = (bc[l * 128 + d] - mean[l * 128 + d]) * s + beta[l * 128 + d];
        } else {
            t = bc[2 * 128 + d];
        }
        tc[i] = t;
    }
    if (i < 3 * 16384) {
        int l = i >> 14, r = (i >> 7) & 127, k = i & 127;
        float s = 1.f;
        if (l < 2) s = gamma[l * 128 + r] * rsqrtf(var[l * 128 + r] + 1e-5f);
        // WT[l][r][k] = W[l][k][r] * sc[l][r]  (BN scale folded into output column)
        WT[i] = __float2bfloat16(Wc[l * 16384 + k * 128 + r] * s);
    }
}

// ---------- pre: hs0 = bf16(dis[n] * x[n,:]) ----------
__global__ __launch_bounds__(256) void k_pre(const float* __restrict__ x,
                                             const float* __restrict__ dis,
                                             u32* __restrict__ hs) {
    int i = blockIdx.x * 256 + threadIdx.x;   // u32 slot: node = i>>6
    if (i < NN * 64) {
        float dn = dis[i >> 6];
        float2 v = ((const float2*)x)[i];
        hs[i] = bpack(v.x * dn, v.y * dn);
    }
}

// ---------- fused aggregate + transform v2: 256-thread blocks (r16, proven) ----------
// 4 waves x 4 nodes (degree-matched via in-bucket perm). Gather phase is the
// proven 61us shape; MFMA epilogue overlaps across the 8+ resident blocks/CU.
template <int PRESCALE>
__global__ __launch_bounds__(256) void k_aggT2(const u32* __restrict__ hin,
                                               const int* __restrict__ offs,
                                               const int* __restrict__ src,
                                               const float* __restrict__ dis,
                                               const int* __restrict__ perm,
                                               const __hip_bfloat16* __restrict__ WT,
                                               const float* __restrict__ tc,
                                               u32* __restrict__ hout) {
    __shared__ u32   Atile[16][68];
    __shared__ float Otile[16][132];
    int tid = threadIdx.x;
    int w = tid >> 6, lane = tid & 63;
    int base = blockIdx.x * 16;
    int nodes[4];
    float dns[4];
#pragma unroll
    for (int i = 0; i < 4; i++) {
        int slot = w * 4 + i;
        int node = __builtin_amdgcn_readfirstlane(perm[base + slot]);
        nodes[i] = node;
        int e0 = __builtin_amdgcn_readfirstlane(offs[node]);
        int e1 = __builtin_amdgcn_readfirstlane(offs[node + 1]);
        u32 self = hin[((u32)node << 6) + lane];
        f32x2 acc = {blo(self), bhi(self)};
        int e = e0;
        for (; e + 16 <= e1; e += 16) {
            u32 u[16];
#pragma unroll
            for (int j = 0; j < 16; j++) {
                u32 s = (u32)src[e + j];
                u[j] = hin[(s << 6) + lane];
            }
#pragma unroll
            for (int j = 0; j < 16; j++) {
                f32x2 v = {blo(u[j]), bhi(u[j])};
                acc += v;
            }
        }
        for (; e + 8 <= e1; e += 8) {
            u32 u[8];
#pragma unroll
            for (int j = 0; j < 8; j++) {
                u32 s = (u32)src[e + j];
                u[j] = hin[(s << 6) + lane];
            }
#pragma unroll
            for (int j = 0; j < 8; j++) {
                f32x2 v = {blo(u[j]), bhi(u[j])};
                acc += v;
            }
        }
        for (; e < e1; e++) {
            u32 u = hin[((u32)src[e] << 6) + lane];
            f32x2 v = {blo(u), bhi(u)};
            acc += v;
        }
        float dn = dis[node];
        dns[i] = dn;
        Atile[slot][lane] = bpack(acc.x * dn, acc.y * dn);
    }
    __syncthreads();
    // MFMA: wave w computes col-tiles 2w and 2w+1 of [16x128] = A @ (W*sc)
    int lg = lane >> 4, lr = lane & 15;
#pragma unroll
    for (int t = 0; t < 2; t++) {
        int ct = w * 2 + t;
        f32x4 c4 = {0.f, 0.f, 0.f, 0.f};
#pragma unroll
        for (int kk = 0; kk < 4; kk++) {
            bf16x8 a = *(const bf16x8*)&Atile[lr][kk * 16 + lg * 4];
            bf16x8 b = *(const bf16x8*)(WT + (size_t)(ct * 16 + lr) * 128 + kk * 32 + lg * 8);
            c4 = __builtin_amdgcn_mfma_f32_16x16x32_bf16(a, b, c4, 0, 0, 0);
        }
        // C/D: col = lane&15 (-> global col ct*16+lr), row = lg*4 + r
#pragma unroll
        for (int r = 0; r < 4; r++)
            Otile[lg * 4 + r][ct * 16 + lr] = c4[r];
    }
    __syncthreads();
    // epilogue: wave w writes its own 4 nodes' rows, coalesced
    int d0 = lane * 2;
    float t0 = tc[d0], t1 = tc[d0 + 1];
#pragma unroll
    for (int i = 0; i < 4; i++) {
        int slot = w * 4 + i;
        float r0 = Otile[slot][d0]     + t0;
        float r1 = Otile[slot][d0 + 1] + t1;
        r0 = r0 > 0.f ? r0 : 0.03f * r0;
        r1 = r1 > 0.f ? r1 : 0.03f * r1;
        if (PRESCALE) { r0 *= dns[i]; r1 *= dns[i]; }
        hout[((u32)nodes[i] << 6) + lane] = bpack(r0, r1);
    }
}

// ---------- global mean pool: parallel partial sums (batch sorted) ----------
__global__ __launch_bounds__(64) void k_pool(const u32* __restrict__ h,
                                             const int* __restrict__ batch,
                                             float* __restrict__ pooled,
                                             float* __restrict__ counts) {
    int lane = threadIdx.x;  // covers 2 feature cols
    int n0 = blockIdx.x * PPN;
    if (n0 >= NN) return;
    int n1 = n0 + PPN;
    if (n1 > NN) n1 = NN;
    float a0 = 0.f, a1 = 0.f, cnt = 0.f;
    int g = batch[n0];
    for (int n = n0; n < n1; n++) {
        int bg = batch[n];
        if (bg != g) {
            atomicAdd(&pooled[g * 128 + lane * 2], a0);
            atomicAdd(&pooled[g * 128 + lane * 2 + 1], a1);
            if (lane == 0) atomicAdd(&counts[g], cnt);
            a0 = 0.f; a1 = 0.f; cnt = 0.f; g = bg;
        }
        u32 u = h[(u32)n * 64u + lane];
        a0 += blo(u); a1 += bhi(u);
        cnt += 1.f;
    }
    atomicAdd(&pooled[g * 128 + lane * 2], a0);
    atomicAdd(&pooled[g * 128 + lane * 2 + 1], a1);
    if (lane == 0) atomicAdd(&counts[g], cnt);
}

// ---------- head ----------
__global__ void k_head(const float* __restrict__ pooled, const float* __restrict__ counts,
                       const float* __restrict__ w, const float* __restrict__ b,
                       float* __restrict__ out) {
    int i = blockIdx.x * blockDim.x + threadIdx.x;
    if (i >= GG * CC) return;
    int g = i / CC, c = i % CC;
    float cnt = counts[g];
    cnt = cnt > 1.f ? cnt : 1.f;
    float inv = 1.f / cnt;
    const float* p = &pooled[g * 128];
    const float* ww = &w[c * 128];
    float acc = 0.f;
    for (int d = 0; d < 128; d++) acc += p[d] * ww[d];
    out[i] = acc * inv + b[c];
}

extern "C" void kernel_launch(void* const* d_in, const int* in_sizes, int n_in,
                              void* d_out, int out_size, void* d_ws, size_t ws_size,
                              hipStream_t stream) {
    const float* x     = (const float*)d_in[0];
    const int*   ei    = (const int*)d_in[1];
    const int*   row   = ei;
    const int*   col   = ei + EE;
    const int*   batch = (const int*)d_in[2];
    const float* Wc    = (const float*)d_in[3];
    const float* bc    = (const float*)d_in[4];
    const float* gamma = (const float*)d_in[5];
    const float* beta  = (const float*)d_in[6];
    const float* mean  = (const float*)d_in[7];
    const float* var   = (const float*)d_in[8];
    const float* lw    = (const float*)d_in[9];
    const float* lb    = (const float*)d_in[10];
    float* out = (float*)d_out;

    char* p = (char*)d_ws;
    auto alloc = [&](size_t bytes) -> char* {
        char* r = p;
        p += (bytes + 255) & ~(size_t)255;
        return r;
    };
    float* dis    = (float*)alloc((size_t)NN * 4);
    int*   offs   = (int*)alloc((size_t)(NN + 1) * 4);
    int*   perm   = (int*)alloc((size_t)NN * 4);
    int*   bhist  = (int*)alloc((size_t)NB * CPAD * 4);
    int*   boffs  = (int*)alloc((size_t)(NB + 1) * 4);
    int*   bcur   = (int*)alloc((size_t)NB * CPAD * 4);
    int*   src    = (int*)alloc((size_t)EE * 4);
    __hip_bfloat16* WT = (__hip_bfloat16*)alloc((size_t)3 * 16384 * 2);
    float* tc     = (float*)alloc((size_t)3 * 128 * 4);
    float* pooled = (float*)alloc((size_t)GG * 128 * 4);
    float* counts = (float*)alloc((size_t)GG * 4);
    __hip_bfloat16* h0b = (__hip_bfloat16*)alloc((size_t)NN * 128 * 2);
    __hip_bfloat16* h1b = (__hip_bfloat16*)alloc((size_t)NN * 128 * 2);
    u32* pairs = (u32*)h0b;  // alias: pairs dead before k_pre writes h0b

    hipMemsetAsync(bhist, 0, (size_t)NB * CPAD * 4, stream);
    hipMemsetAsync(pooled, 0, (size_t)GG * 128 * 4, stream);
    hipMemsetAsync(counts, 0, (size_t)GG * 4, stream);

    const int eb_grid = (EE + 256 * VPT - 1) / (256 * VPT);
    k_bcount<<<eb_grid, 256, 0, stream>>>(col, bhist);
    k_bscan<<<1, 512, 0, stream>>>(bhist, boffs, bcur);
    k_part<<<eb_grid, 256, 0, stream>>>(row, col, bcur, pairs);
    k_sort<<<NB, 256, 0, stream>>>(pairs, boffs, offs, dis, src, perm);
    k_prep<<<192, 256, 0, stream>>>(Wc, bc, gamma, beta, mean, var, WT, tc);
    k_pre<<<(NN * 64 + 255) / 256, 256, 0, stream>>>(x, dis, (u32*)h0b);  // after k_sort (pairs alias)

    const int fused_grid = NN / 16;  // 6250, exact

    k_aggT2<1><<<fused_grid, 256, 0, stream>>>((const u32*)h0b, offs, src, dis, perm, WT,           tc,       (u32*)h1b);
    k_aggT2<1><<<fused_grid, 256, 0, stream>>>((const u32*)h1b, offs, src, dis, perm, WT + 16384,   tc + 128, (u32*)h0b);
    k_aggT2<0><<<fused_grid, 256, 0, stream>>>((const u32*)h0b, offs, src, dis, perm, WT + 2*16384, tc + 256, (u32*)h1b);

    k_pool<<<(NN + PPN - 1) / PPN, 64, 0, stream>>>((const u32*)h1b, batch, pooled, counts);
    k_head<<<(GG * CC + 255) / 256, 256, 0, stream>>>(pooled, counts, lw, lb, out);
}

// Round 19
// 330.306 us; speedup vs baseline: 1.3198x; 1.2917x over previous
//
#include <hip/hip_runtime.h>
#include <hip/hip_bf16.h>

#define NN 100000
#define EE 1600000
#define DD 128
#define GG 128
#define CC 10
#define NPB 256      // nodes per bucket (power of 2)
#define NB 391       // ceil(NN/NPB)
#define SCAP 5120    // LDS slot capacity per bucket (mean 4092, sigma ~64)
#define VPT 16       // edges per thread in k_part (391 blocks — aggregation cost scales w/ blocks)
#define CPAD 32      // padded counter stride (ints) = 128B per counter
#define PPN 64       // nodes per pool block
#define DB 256       // degree bins (clamped)
#define PCAP 4608    // padded pairs capacity per bucket (mean 4096 + 8 sigma)

typedef __attribute__((ext_vector_type(8))) short bf16x8;
typedef __attribute__((ext_vector_type(4))) float f32x4;
typedef __attribute__((ext_vector_type(2))) float f32x2;
typedef unsigned int u32;

__device__ inline float blo(u32 u) { return __uint_as_float(u << 16); }
__device__ inline float bhi(u32 u) { return __uint_as_float(u & 0xffff0000u); }
// pack two floats to bf16x2 (RNE)
__device__ inline u32 bpack(float x, float y) {
    u32 bx = __float_as_uint(x);
    u32 by = __float_as_uint(y);
    bx = (bx + 0x7fffu + ((bx >> 16) & 1u)) >> 16;
    by = (by + 0x7fffu + ((by >> 16) & 1u)) & 0xffff0000u;
    return bx | by;
}

// ---------- partition edges into PADDED bucket regions (no pre-count pass) ----------
// bcur starts at 0; bucket b's region is pairs[b*PCAP ...]. One edge pass total.
__global__ __launch_bounds__(256) void k_part(const int* __restrict__ row, const int* __restrict__ col,
                                              int* __restrict__ bcur, u32* __restrict__ pairs) {
    __shared__ int lhist[NB];
    __shared__ int gbase[NB];
    __shared__ int lcur[NB];
    int tid = threadIdx.x;
    for (int b = tid; b < NB; b += 256) lhist[b] = 0;
    __syncthreads();
    int base = blockIdx.x * (256 * VPT);
    u32 v[VPT];
    int bb[VPT];
#pragma unroll
    for (int j = 0; j < VPT; j++) {
        int e = base + j * 256 + tid;
        if (e < EE) {
            int r = row[e], c = col[e];
            v[j] = ((u32)r << 8) | (u32)(c & 255);
            bb[j] = c >> 8;
            atomicAdd(&lhist[bb[j]], 1);
        } else {
            bb[j] = -1;
        }
    }
    __syncthreads();
    for (int b = tid; b < NB; b += 256) {
        int h = lhist[b];
        gbase[b] = h ? atomicAdd(&bcur[b * CPAD], h) : 0;
        lcur[b] = 0;
    }
    __syncthreads();
#pragma unroll
    for (int j = 0; j < VPT; j++) {
        if (bb[j] >= 0) {
            int slot = gbase[bb[j]] + atomicAdd(&lcur[bb[j]], 1);
            pairs[(u32)bb[j] * PCAP + slot] = v[j];
        }
    }
}

// ---------- bucket counts (= final bcur) -> exclusive scan -> boffs ----------
__global__ __launch_bounds__(512) void k_bscan(const int* __restrict__ bcur,
                                               int* __restrict__ boffs) {
    __shared__ int s[512];
    int tid = threadIdx.x;
    int c = (tid < NB) ? bcur[tid * CPAD] : 0;
    s[tid] = c;
    __syncthreads();
    for (int off = 1; off < 512; off <<= 1) {
        int v = (tid >= off) ? s[tid - off] : 0;
        __syncthreads();
        s[tid] += v;
        __syncthreads();
    }
    int excl = s[tid] - c;
    if (tid < NB) boffs[tid] = excl;
    if (tid == NB - 1) boffs[NB] = excl + c;  // == EE
}

// ---------- per-bucket: node counts -> offs+dis+deg, LDS counting sort -> src ----------
// reads padded region pairs[b*PCAP..], writes compact src at boffs[b].
__global__ __launch_bounds__(256) void k_sort(const u32* __restrict__ pairs,
                                              const int* __restrict__ boffs,
                                              int* __restrict__ offs,
                                              float* __restrict__ dis,
                                              int* __restrict__ deg,
                                              int* __restrict__ src) {
    int b = blockIdx.x;
    int tid = threadIdx.x;
    int nstart = b << 8;
    int nvalid = NN - nstart;           // valid nodes in this bucket
    if (nvalid > NPB) nvalid = NPB;
    int base = boffs[b];
    int cnt = boffs[b + 1] - base;
    u32 pbase = (u32)b * PCAP;
    __shared__ int lcnt[NPB];
    __shared__ int lscan[NPB];
    __shared__ int lcur[NPB];
    __shared__ int lsrc[SCAP];
    lcnt[tid] = 0;
    __syncthreads();
    for (int i = tid; i < cnt; i += 256)
        atomicAdd(&lcnt[pairs[pbase + i] & 255u], 1);
    __syncthreads();
    int c = lcnt[tid];
    lscan[tid] = c;
    __syncthreads();
    for (int off = 1; off < 256; off <<= 1) {
        int v = (tid >= off) ? lscan[tid - off] : 0;
        __syncthreads();
        lscan[tid] += v;
        __syncthreads();
    }
    int excl = lscan[tid] - c;
    if (tid < nvalid) {
        offs[nstart + tid] = base + excl;
        dis[nstart + tid] = rsqrtf((float)(c + 1));  // degree includes self-loop
        deg[nstart + tid] = c;
    }
    if (b == NB - 1 && tid == 255) offs[NN] = EE;
    lcur[tid] = excl;
    __syncthreads();
    if (cnt <= SCAP) {
        for (int i = tid; i < cnt; i += 256) {
            u32 v = pairs[pbase + i];
            int slot = atomicAdd(&lcur[v & 255u], 1);
            lsrc[slot] = (int)(v >> 8);
        }
        __syncthreads();
        for (int i = tid; i < cnt; i += 256)
            src[base + i] = lsrc[i];
    } else {
        // fallback (not expected on this input): place directly to global
        for (int i = tid; i < cnt; i += 256) {
            u32 v = pairs[pbase + i];
            int slot = base + atomicAdd(&lcur[v & 255u], 1);
            src[slot] = (int)(v >> 8);
        }
    }
}

// ---------- degree histogram (block-aggregated) ----------
__global__ __launch_bounds__(256) void k_dhist(const int* __restrict__ deg,
                                               int* __restrict__ dh) {
    __shared__ int lh[DB];
    int tid = threadIdx.x;
    lh[tid] = 0;
    __syncthreads();
    int base = blockIdx.x * 1024;
#pragma unroll
    for (int j = 0; j < 4; j++) {
        int n = base + j * 256 + tid;
        if (n < NN) {
            int d = deg[n]; if (d > 255) d = 255;
            atomicAdd(&lh[d], 1);
        }
    }
    __syncthreads();
    int h = lh[tid];
    if (h) atomicAdd(&dh[tid * CPAD], h);
}

// ---------- degree-bin exclusive scan -> cursors ----------
__global__ __launch_bounds__(256) void k_dscan(const int* __restrict__ dh,
                                               int* __restrict__ dcur) {
    __shared__ int s[DB];
    int tid = threadIdx.x;
    int c = dh[tid * CPAD];
    s[tid] = c;
    __syncthreads();
    for (int off = 1; off < DB; off <<= 1) {
        int v = (tid >= off) ? s[tid - off] : 0;
        __syncthreads();
        s[tid] += v;
        __syncthreads();
    }
    dcur[tid * CPAD] = s[tid] - c;
}

// ---------- degree-sorted permutation (block-aggregated placement) ----------
__global__ __launch_bounds__(256) void k_dfill(const int* __restrict__ deg,
                                               int* __restrict__ dcur,
                                               int* __restrict__ perm) {
    __shared__ int lh[DB];
    __shared__ int gb[DB];
    __shared__ int lc[DB];
    int tid = threadIdx.x;
    lh[tid] = 0;
    __syncthreads();
    int base = blockIdx.x * 1024;
    int d[4];
#pragma unroll
    for (int j = 0; j < 4; j++) {
        int n = base + j * 256 + tid;
        if (n < NN) {
            d[j] = deg[n]; if (d[j] > 255) d[j] = 255;
            atomicAdd(&lh[d[j]], 1);
        } else d[j] = -1;
    }
    __syncthreads();
    int h = lh[tid];
    gb[tid] = h ? atomicAdd(&dcur[tid * CPAD], h) : 0;
    lc[tid] = 0;
    __syncthreads();
#pragma unroll
    for (int j = 0; j < 4; j++) {
        if (d[j] >= 0) {
            int r = atomicAdd(&lc[d[j]], 1);
            perm[gb[d[j]] + r] = base + j * 256 + tid;
        }
    }
}

// ---------- params prep: W^T -> bf16 with BN scale folded into columns ----------
__global__ void k_prep(const float* __restrict__ Wc, const float* __restrict__ bc,
                       const float* __restrict__ gamma, const float* __restrict__ beta,
                       const float* __restrict__ mean, const float* __restrict__ var,
                       __hip_bfloat16* __restrict__ WT,
                       float* __restrict__ tc) {
    int i = blockIdx.x * 256 + threadIdx.x;
    if (i < 3 * 128) {
        int l = i >> 7, d = i & 127;
        float t;
        if (l < 2) {
            float s = gamma[l * 128 + d] * rsqrtf(var[l * 128 + d] + 1e-5f);
            t = (bc[l * 128 + d] - mean[l * 128 + d]) * s + beta[l * 128 + d];
        } else {
            t = bc[2 * 128 + d];
        }
        tc[i] = t;
    }
    if (i < 3 * 16384) {
        int l = i >> 14, r = (i >> 7) & 127, k = i & 127;
        float s = 1.f;
        if (l < 2) s = gamma[l * 128 + r] * rsqrtf(var[l * 128 + r] + 1e-5f);
        // WT[l][r][k] = W[l][k][r] * sc[l][r]  (BN scale folded into output column)
        WT[i] = __float2bfloat16(Wc[l * 16384 + k * 128 + r] * s);
    }
}

// ---------- pre: hs0 = bf16(dis[n] * x[n,:]) ----------
__global__ __launch_bounds__(256) void k_pre(const float* __restrict__ x,
                                             const float* __restrict__ dis,
                                             u32* __restrict__ hs) {
    int i = blockIdx.x * 256 + threadIdx.x;   // u32 slot: node = i>>6
    if (i < NN * 64) {
        float dn = dis[i >> 6];
        float2 v = ((const float2*)x)[i];
        hs[i] = bpack(v.x * dn, v.y * dn);
    }
}

// ---------- fused aggregate + transform v2: 256-thread blocks (r16, proven) ----------
// 4 waves x 4 nodes (degree-matched via global degree-sorted perm). Gather phase
// is the proven 61us shape; MFMA epilogue overlaps across 8+ resident blocks/CU.
template <int PRESCALE>
__global__ __launch_bounds__(256) void k_aggT2(const u32* __restrict__ hin,
                                               const int* __restrict__ offs,
                                               const int* __restrict__ src,
                                               const float* __restrict__ dis,
                                               const int* __restrict__ perm,
                                               const __hip_bfloat16* __restrict__ WT,
                                               const float* __restrict__ tc,
                                               u32* __restrict__ hout) {
    __shared__ u32   Atile[16][68];
    __shared__ float Otile[16][132];
    int tid = threadIdx.x;
    int w = tid >> 6, lane = tid & 63;
    int base = blockIdx.x * 16;
    int nodes[4];
    float dns[4];
#pragma unroll
    for (int i = 0; i < 4; i++) {
        int slot = w * 4 + i;
        int node = __builtin_amdgcn_readfirstlane(perm[base + slot]);
        nodes[i] = node;
        int e0 = __builtin_amdgcn_readfirstlane(offs[node]);
        int e1 = __builtin_amdgcn_readfirstlane(offs[node + 1]);
        u32 self = hin[((u32)node << 6) + lane];
        f32x2 acc = {blo(self), bhi(self)};
        int e = e0;
        for (; e + 16 <= e1; e += 16) {
            u32 u[16];
#pragma unroll
            for (int j = 0; j < 16; j++) {
                u32 s = (u32)src[e + j];
                u[j] = hin[(s << 6) + lane];
            }
#pragma unroll
            for (int j = 0; j < 16; j++) {
                f32x2 v = {blo(u[j]), bhi(u[j])};
                acc += v;
            }
        }
        for (; e + 8 <= e1; e += 8) {
            u32 u[8];
#pragma unroll
            for (int j = 0; j < 8; j++) {
                u32 s = (u32)src[e + j];
                u[j] = hin[(s << 6) + lane];
            }
#pragma unroll
            for (int j = 0; j < 8; j++) {
                f32x2 v = {blo(u[j]), bhi(u[j])};
                acc += v;
            }
        }
        for (; e < e1; e++) {
            u32 u = hin[((u32)src[e] << 6) + lane];
            f32x2 v = {blo(u), bhi(u)};
            acc += v;
        }
        float dn = dis[node];
        dns[i] = dn;
        Atile[slot][lane] = bpack(acc.x * dn, acc.y * dn);
    }
    __syncthreads();
    // MFMA: wave w computes col-tiles 2w and 2w+1 of [16x128] = A @ (W*sc)
    int lg = lane >> 4, lr = lane & 15;
#pragma unroll
    for (int t = 0; t < 2; t++) {
        int ct = w * 2 + t;
        f32x4 c4 = {0.f, 0.f, 0.f, 0.f};
#pragma unroll
        for (int kk = 0; kk < 4; kk++) {
            bf16x8 a = *(const bf16x8*)&Atile[lr][kk * 16 + lg * 4];
            bf16x8 b = *(const bf16x8*)(WT + (size_t)(ct * 16 + lr) * 128 + kk * 32 + lg * 8);
            c4 = __builtin_amdgcn_mfma_f32_16x16x32_bf16(a, b, c4, 0, 0, 0);
        }
        // C/D: col = lane&15 (-> global col ct*16+lr), row = lg*4 + r
#pragma unroll
        for (int r = 0; r < 4; r++)
            Otile[lg * 4 + r][ct * 16 + lr] = c4[r];
    }
    __syncthreads();
    // epilogue: wave w writes its own 4 nodes' rows, coalesced
    int d0 = lane * 2;
    float t0 = tc[d0], t1 = tc[d0 + 1];
#pragma unroll
    for (int i = 0; i < 4; i++) {
        int slot = w * 4 + i;
        float r0 = Otile[slot][d0]     + t0;
        float r1 = Otile[slot][d0 + 1] + t1;
        r0 = r0 > 0.f ? r0 : 0.03f * r0;
        r1 = r1 > 0.f ? r1 : 0.03f * r1;
        if (PRESCALE) { r0 *= dns[i]; r1 *= dns[i]; }
        hout[((u32)nodes[i] << 6) + lane] = bpack(r0, r1);
    }
}

// ---------- global mean pool: parallel partial sums (batch sorted) ----------
__global__ __launch_bounds__(64) void k_pool(const u32* __restrict__ h,
                                             const int* __restrict__ batch,
                                             float* __restrict__ pooled,
                                             float* __restrict__ counts) {
    int lane = threadIdx.x;  // covers 2 feature cols
    int n0 = blockIdx.x * PPN;
    if (n0 >= NN) return;
    int n1 = n0 + PPN;
    if (n1 > NN) n1 = NN;
    float a0 = 0.f, a1 = 0.f, cnt = 0.f;
    int g = batch[n0];
    for (int n = n0; n < n1; n++) {
        int bg = batch[n];
        if (bg != g) {
            atomicAdd(&pooled[g * 128 + lane * 2], a0);
            atomicAdd(&pooled[g * 128 + lane * 2 + 1], a1);
            if (lane == 0) atomicAdd(&counts[g], cnt);
            a0 = 0.f; a1 = 0.f; cnt = 0.f; g = bg;
        }
        u32 u = h[(u32)n * 64u + lane];
        a0 += blo(u); a1 += bhi(u);
        cnt += 1.f;
    }
    atomicAdd(&pooled[g * 128 + lane * 2], a0);
    atomicAdd(&pooled[g * 128 + lane * 2 + 1], a1);
    if (lane == 0) atomicAdd(&counts[g], cnt);
}

// ---------- head ----------
__global__ void k_head(const float* __restrict__ pooled, const float* __restrict__ counts,
                       const float* __restrict__ w, const float* __restrict__ b,
                       float* __restrict__ out) {
    int i = blockIdx.x * blockDim.x + threadIdx.x;
    if (i >= GG * CC) return;
    int g = i / CC, c = i % CC;
    float cnt = counts[g];
    cnt = cnt > 1.f ? cnt : 1.f;
    float inv = 1.f / cnt;
    const float* p = &pooled[g * 128];
    const float* ww = &w[c * 128];
    float acc = 0.f;
    for (int d = 0; d < 128; d++) acc += p[d] * ww[d];
    out[i] = acc * inv + b[c];
}

extern "C" void kernel_launch(void* const* d_in, const int* in_sizes, int n_in,
                              void* d_out, int out_size, void* d_ws, size_t ws_size,
                              hipStream_t stream) {
    const float* x     = (const float*)d_in[0];
    const int*   ei    = (const int*)d_in[1];
    const int*   row   = ei;
    const int*   col   = ei + EE;
    const int*   batch = (const int*)d_in[2];
    const float* Wc    = (const float*)d_in[3];
    const float* bc    = (const float*)d_in[4];
    const float* gamma = (const float*)d_in[5];
    const float* beta  = (const float*)d_in[6];
    const float* mean  = (const float*)d_in[7];
    const float* var   = (const float*)d_in[8];
    const float* lw    = (const float*)d_in[9];
    const float* lb    = (const float*)d_in[10];
    float* out = (float*)d_out;

    char* p = (char*)d_ws;
    auto alloc = [&](size_t bytes) -> char* {
        char* r = p;
        p += (bytes + 255) & ~(size_t)255;
        return r;
    };
    float* dis    = (float*)alloc((size_t)NN * 4);
    int*   offs   = (int*)alloc((size_t)(NN + 1) * 4);
    int*   deg    = (int*)alloc((size_t)NN * 4);
    int*   perm   = (int*)alloc((size_t)NN * 4);
    int*   boffs  = (int*)alloc((size_t)(NB + 1) * 4);
    int*   bcur   = (int*)alloc((size_t)NB * CPAD * 4);
    int*   dh     = (int*)alloc((size_t)DB * CPAD * 4);
    int*   dcur   = (int*)alloc((size_t)DB * CPAD * 4);
    int*   src    = (int*)alloc((size_t)EE * 4);
    __hip_bfloat16* WT = (__hip_bfloat16*)alloc((size_t)3 * 16384 * 2);
    float* tc     = (float*)alloc((size_t)3 * 128 * 4);
    float* pooled = (float*)alloc((size_t)GG * 128 * 4);
    float* counts = (float*)alloc((size_t)GG * 4);
    __hip_bfloat16* h0b = (__hip_bfloat16*)alloc((size_t)NN * 128 * 2);
    __hip_bfloat16* h1b = (__hip_bfloat16*)alloc((size_t)NN * 128 * 2);
    u32* pairs = (u32*)h0b;  // alias: padded pairs (391*4608*4B = 7.2MB < 25.6MB); dead before k_pre

    hipMemsetAsync(bcur, 0, (size_t)NB * CPAD * 4, stream);
    hipMemsetAsync(dh, 0, (size_t)DB * CPAD * 4, stream);
    hipMemsetAsync(pooled, 0, (size_t)GG * 128 * 4, stream);
    hipMemsetAsync(counts, 0, (size_t)GG * 4, stream);

    const int eb_grid = (EE + 256 * VPT - 1) / (256 * VPT);
    const int nd_grid = (NN + 1023) / 1024;
    k_part<<<eb_grid, 256, 0, stream>>>(row, col, bcur, pairs);
    k_bscan<<<1, 512, 0, stream>>>(bcur, boffs);
    k_sort<<<NB, 256, 0, stream>>>(pairs, boffs, offs, dis, deg, src);
    k_dhist<<<nd_grid, 256, 0, stream>>>(deg, dh);
    k_dscan<<<1, 256, 0, stream>>>(dh, dcur);
    k_dfill<<<nd_grid, 256, 0, stream>>>(deg, dcur, perm);
    k_prep<<<192, 256, 0, stream>>>(Wc, bc, gamma, beta, mean, var, WT, tc);
    k_pre<<<(NN * 64 + 255) / 256, 256, 0, stream>>>(x, dis, (u32*)h0b);  // after k_sort (pairs alias)

    const int fused_grid = NN / 16;  // 6250, exact

    k_aggT2<1><<<fused_grid, 256, 0, stream>>>((const u32*)h0b, offs, src, dis, perm, WT,           tc,       (u32*)h1b);
    k_aggT2<1><<<fused_grid, 256, 0, stream>>>((const u32*)h1b, offs, src, dis, perm, WT + 16384,   tc + 128, (u32*)h0b);
    k_aggT2<0><<<fused_grid, 256, 0, stream>>>((const u32*)h0b, offs, src, dis, perm, WT + 2*16384, tc + 256, (u32*)h1b);

    k_pool<<<(NN + PPN - 1) / PPN, 64, 0, stream>>>((const u32*)h1b, batch, pooled, counts);
    k_head<<<(GG * CC + 255) / 256, 256, 0, stream>>>(pooled, counts, lw, lb, out);
}